// Round 19
// baseline (205.472 us; speedup 1.0000x reference)
//
#include <hip/hip_runtime.h>
#include <hip/hip_bf16.h>

// MHA: fused QKV proj (f32 A fused-cvt, V-GEMM writes V^T) -> flash attn
// (32x32 MFMA, QBLK=32/wave, in-register P via v_permlane32_swap) -> out proj.
// R19 = R18 with permlane operand order corrected: swap(T0,T2) exchanges
// T0_hi <-> T2_lo (vdst hi-lanes <-> vsrc lo-lanes per ISA).
#define DIN   1024
#define HEADS 16
#define DK    64
#define BATCH 4
#define SEQ   2048
#define MROWS (BATCH*SEQ)   /* 8192 */
#define HD    (HEADS*DK)    /* 1024 */

typedef unsigned short u16;
typedef unsigned int   u32;
typedef __attribute__((ext_vector_type(8))) short v8s;
typedef __attribute__((ext_vector_type(4))) float v4f;
typedef __attribute__((ext_vector_type(16))) float v16f;

__device__ __forceinline__ u16 f2bf(float x) {
  union { float f; u32 u; } v; v.f = x;
  u32 r = v.u + 0x7FFFu + ((v.u >> 16) & 1u);
  return (u16)(r >> 16);
}
__device__ __forceinline__ int cvtpk(float lo, float hi) {
  int r;
  asm("v_cvt_pk_bf16_f32 %0, %1, %2" : "=v"(r) : "v"(lo), "v"(hi));
  return r;
}
__device__ __forceinline__ float max3f(float a, float b, float c) {
  float r;
  asm("v_max3_f32 %0, %1, %2, %3" : "=v"(r) : "v"(a), "v"(b), "v"(c));
  return r;
}
__device__ __forceinline__ void gload16(const void* g, void* l) {
  __builtin_amdgcn_global_load_lds(
      (__attribute__((address_space(1))) void*)(uintptr_t)(g),
      (__attribute__((address_space(3))) void*)(uintptr_t)(l), 16, 0, 0);
}
// swizzled access into flat [64 rows][8 units of 16B] tile: phys unit = u ^ (row&7)
__device__ __forceinline__ v8s lds_read_swz(const u16* base, int row, int unit) {
  return *(const v8s*)((const char*)base + (row << 7) + (((unit) ^ (row & 7)) << 4));
}

// ---- weight transpose x4: W[k][n] f32 -> Wt[n][k] bf16 ----
__global__ __launch_bounds__(256) void wtrans4_kernel(
    const float* __restrict__ w0, const float* __restrict__ w1,
    const float* __restrict__ w2, const float* __restrict__ w3,
    u16* __restrict__ o0, u16* __restrict__ o1,
    u16* __restrict__ o2, u16* __restrict__ o3) {
  __shared__ float tile[64][65];
  const float* in = blockIdx.z == 0 ? w0 : blockIdx.z == 1 ? w1 : blockIdx.z == 2 ? w2 : w3;
  u16* out = blockIdx.z == 0 ? o0 : blockIdx.z == 1 ? o1 : blockIdx.z == 2 ? o2 : o3;
  int bx = blockIdx.x * 64;
  int by = blockIdx.y * 64;
  for (int i = threadIdx.x; i < 64 * 64; i += 256) {
    int r = i >> 6, c = i & 63;
    tile[r][c] = in[(size_t)(by + r) * DIN + bx + c];
  }
  __syncthreads();
  for (int i = threadIdx.x; i < 64 * 64; i += 256) {
    int r = i >> 6, c = i & 63;
    out[(size_t)(bx + r) * DIN + by + c] = f2bf(tile[c][r]);
  }
}

// ---- fused QKV 128x128 GEMM: 1536 blocks, which = bid>>9 selects {Q,K,V}.
// A f32 reg-staged + fused cvt (T14); B bf16 DMA dbuf; 1 barrier / K-step. ----
__global__ __launch_bounds__(256) void gemm_qkv_kernel(
    const float* __restrict__ q_in, const float* __restrict__ k_in,
    const float* __restrict__ v_in, const u16* __restrict__ Wtq,
    const u16* __restrict__ Wtk, const u16* __restrict__ Wtv,
    u16* __restrict__ Qb, u16* __restrict__ Kb, u16* __restrict__ VtB) {
  __shared__ u16 A_lds[2][128 * 32];
  __shared__ u16 B_lds[2][128 * 32];
  const int which = blockIdx.x >> 9;  // 0..2
  const float* Ain = which == 0 ? q_in : which == 1 ? k_in : v_in;
  const u16* Bt = which == 0 ? Wtq : which == 1 ? Wtk : Wtv;
  u16* Cout = which == 0 ? Qb : which == 1 ? Kb : VtB;

  const int tid = threadIdx.x;
  const int lane = tid & 63;
  const int wv = tid >> 6;
  const int wm = wv & 1, wn = wv >> 1;
  const int bid = blockIdx.x & 511;
  const int swz = (bid & 7) * 64 + (bid >> 3);  // 512 % 8 == 0, bijective
  const int m0 = (swz >> 3) * 128;
  const int n0 = (swz & 7) * 128;
  const int l15 = lane & 15;
  const int k8 = (lane >> 4) * 8;

  const float* gaf = Ain + (size_t)(m0 + wv * 16 + (lane >> 2)) * DIN + (lane & 3) * 8;
  const u16* gb = Bt + (size_t)(n0 + wv * 16 + (lane >> 2)) * DIN + (lane & 3) * 8;
  u16* la0 = &A_lds[0][wv * 512 + (lane & 63) * 8];
  u16* la1 = &A_lds[1][wv * 512 + (lane & 63) * 8];

  v4f acc[4][4];
#pragma unroll
  for (int i = 0; i < 4; i++)
#pragma unroll
    for (int j = 0; j < 4; j++) acc[i][j] = (v4f)0.f;

  float4 af0, af1, af2, af3;

#define A_GLOAD(ks)                                                   \
  do {                                                                \
    af0 = ((const float4*)(gaf + (ks) * 32))[0];                      \
    af1 = ((const float4*)(gaf + (ks) * 32))[1];                      \
    af2 = ((const float4*)(gaf + (size_t)64 * DIN + (ks) * 32))[0];   \
    af3 = ((const float4*)(gaf + (size_t)64 * DIN + (ks) * 32))[1];   \
  } while (0)
#define A_DSWRITE(b)                                                  \
  do {                                                                \
    int4 w0 = {cvtpk(af0.x, af0.y), cvtpk(af0.z, af0.w),              \
               cvtpk(af1.x, af1.y), cvtpk(af1.z, af1.w)};             \
    int4 w1 = {cvtpk(af2.x, af2.y), cvtpk(af2.z, af2.w),              \
               cvtpk(af3.x, af3.y), cvtpk(af3.z, af3.w)};             \
    *(int4*)((b) ? la1 : la0) = w0;                                   \
    *(int4*)(((b) ? la1 : la0) + 2048) = w1;                          \
  } while (0)
#define B_STAGE(ks, b)                                                \
  do {                                                                \
    gload16(gb + (ks) * 32, &B_lds[b][wv * 512]);                     \
    gload16(gb + (size_t)64 * DIN + (ks) * 32, &B_lds[b][wv * 512 + 2048]); \
  } while (0)

  A_GLOAD(0);
  A_DSWRITE(0);
  B_STAGE(0, 0);
  __syncthreads();

  for (int ks = 0; ks < 32; ++ks) {
    const int buf = ks & 1;
    v8s a[4], b[4];
#pragma unroll
    for (int mi = 0; mi < 4; mi++)
      a[mi] = *(const v8s*)&A_lds[buf][(wm * 64 + mi * 16 + l15) * 32 + k8];
#pragma unroll
    for (int ni = 0; ni < 4; ni++)
      b[ni] = *(const v8s*)&B_lds[buf][(wn * 64 + ni * 16 + l15) * 32 + k8];
    if (ks < 31) {
      A_GLOAD(ks + 1);
      B_STAGE(ks + 1, buf ^ 1);
    }
    __builtin_amdgcn_s_setprio(1);
#pragma unroll
    for (int mi = 0; mi < 4; mi++)
#pragma unroll
      for (int ni = 0; ni < 4; ni++)
        acc[mi][ni] = __builtin_amdgcn_mfma_f32_16x16x32_bf16(a[mi], b[ni], acc[mi][ni], 0, 0, 0);
    __builtin_amdgcn_s_setprio(0);
    if (ks < 31) A_DSWRITE(buf ^ 1);  // vmcnt wait rode under MFMAs
    __syncthreads();
  }
#undef A_GLOAD
#undef A_DSWRITE
#undef B_STAGE

  const int grp = lane >> 4;
#pragma unroll
  for (int mi = 0; mi < 4; mi++) {
#pragma unroll
    for (int ni = 0; ni < 4; ni++) {
      int row = m0 + wm * 64 + mi * 16 + grp * 4;
      int col = n0 + wn * 64 + ni * 16 + l15;
      int w01 = cvtpk(acc[mi][ni][0], acc[mi][ni][1]);
      int w23 = cvtpk(acc[mi][ni][2], acc[mi][ni][3]);
      if (which < 2) {
        u16 h[4] = {(u16)w01, (u16)(w01 >> 16), (u16)w23, (u16)(w23 >> 16)};
#pragma unroll
        for (int r = 0; r < 4; r++) {
          int bb = (row + r) >> 11, ss = (row + r) & 2047;
          int hh = col >> 6, dd = col & 63;
          Cout[((((size_t)bb * HEADS + hh) * SEQ + ss) << 6) + dd] = h[r];
        }
      } else {
        int bb = row >> 11, ss = row & 2047;
        int hh = col >> 6, dd = col & 63;
        int2 w = {w01, w23};
        *(int2*)&Cout[((size_t)(bb * HEADS + hh) * DK + dd) * SEQ + ss] = w;
      }
    }
  }
}

// ---- 128x128 GEMM for Wo: bf16 A via DMA, out f32 linear ----
__global__ __launch_bounds__(256) void gemm_o_kernel(const u16* __restrict__ A,
                                                     const u16* __restrict__ Bt,
                                                     float* __restrict__ Cout) {
  __shared__ u16 A_lds[2][128 * 32];
  __shared__ u16 B_lds[2][128 * 32];
  const int tid = threadIdx.x;
  const int lane = tid & 63;
  const int wv = tid >> 6;
  const int wm = wv & 1, wn = wv >> 1;
  const int bid = blockIdx.x;
  const int swz = (bid & 7) * 64 + (bid >> 3);
  const int m0 = (swz >> 3) * 128;
  const int n0 = (swz & 7) * 128;
  const int l15 = lane & 15;
  const int k8 = (lane >> 4) * 8;

  const u16* ga = A + (size_t)(m0 + wv * 16 + (lane >> 2)) * DIN + (lane & 3) * 8;
  const u16* gb = Bt + (size_t)(n0 + wv * 16 + (lane >> 2)) * DIN + (lane & 3) * 8;

  v4f acc[4][4];
#pragma unroll
  for (int i = 0; i < 4; i++)
#pragma unroll
    for (int j = 0; j < 4; j++) acc[i][j] = (v4f)0.f;

#define G_STAGE(ks, b)                                              \
  do {                                                              \
    gload16(ga + (ks) * 32, &A_lds[b][wv * 512]);                   \
    gload16(ga + (size_t)64 * DIN + (ks) * 32, &A_lds[b][wv * 512 + 2048]); \
    gload16(gb + (ks) * 32, &B_lds[b][wv * 512]);                   \
    gload16(gb + (size_t)64 * DIN + (ks) * 32, &B_lds[b][wv * 512 + 2048]); \
  } while (0)

  G_STAGE(0, 0);
  __syncthreads();
  for (int ks = 0; ks < 32; ++ks) {
    const int buf = ks & 1;
    v8s a[4], b[4];
#pragma unroll
    for (int mi = 0; mi < 4; mi++)
      a[mi] = *(const v8s*)&A_lds[buf][(wm * 64 + mi * 16 + l15) * 32 + k8];
#pragma unroll
    for (int ni = 0; ni < 4; ni++)
      b[ni] = *(const v8s*)&B_lds[buf][(wn * 64 + ni * 16 + l15) * 32 + k8];
    if (ks < 31) G_STAGE(ks + 1, buf ^ 1);
    __builtin_amdgcn_s_setprio(1);
#pragma unroll
    for (int mi = 0; mi < 4; mi++)
#pragma unroll
      for (int ni = 0; ni < 4; ni++)
        acc[mi][ni] = __builtin_amdgcn_mfma_f32_16x16x32_bf16(a[mi], b[ni], acc[mi][ni], 0, 0, 0);
    __builtin_amdgcn_s_setprio(0);
    __syncthreads();
  }
#undef G_STAGE

  const int grp = lane >> 4;
#pragma unroll
  for (int mi = 0; mi < 4; mi++) {
#pragma unroll
    for (int ni = 0; ni < 4; ni++) {
#pragma unroll
      for (int r = 0; r < 4; r++) {
        int row = m0 + wm * 64 + mi * 16 + grp * 4 + r;
        int col = n0 + wn * 64 + ni * 16 + l15;
        Cout[(size_t)row * HD + col] = acc[mi][ni][r];
      }
    }
  }
}

// ---- flash attention: 32x32x16 MFMA, 4 waves x QBLK=32 (128 q/block),
// swapped QK^T (lane owns one q column), in-register P via permlane32_swap,
// XOR-swizzled K/V LDS, T14 staging.  No P_lds. ----
__global__ __launch_bounds__(256) void attn_kernel(const u16* __restrict__ Q,
                                                   const u16* __restrict__ Kmat,
                                                   const u16* __restrict__ Vt,
                                                   u16* __restrict__ AO) {
  __shared__ u16 K_lds[64 * 64];   // [key][d] swizzled, 128B rows
  __shared__ u16 V_lds[64 * 64];   // [d][key] swizzled

  const int tid = threadIdx.x;
  const int lane = tid & 63;
  const int wv = tid >> 6;         // 0..3
  const int l31 = lane & 31;
  const int h = lane >> 5;         // half: 0,1

  const int bid = blockIdx.x;                    // 1024 blocks
  const int swz = (bid & 7) * 128 + (bid >> 3);  // 8 bh per XCD -> K/V L2-fit
  const int bh = swz >> 4;
  const int qt = swz & 15;
  const size_t base = (size_t)bh * SEQ * DK;

  // Q as B-fragment of 32x32x16: B[k=d][n=q], lane: q=l31, d = ks*16 + h*8 + j
  v8s qf[4];
  {
    const int q = qt * 128 + wv * 32 + l31;
    const u16* qp = Q + base + (size_t)q * DK + h * 8;
    const float SCL = 0.125f * 1.44269504f;  // 1/sqrt(dk) * log2(e)
#pragma unroll
    for (int ks = 0; ks < 4; ks++) {
      qf[ks] = *(const v8s*)(qp + ks * 16);
#pragma unroll
      for (int j = 0; j < 8; j++) {
        union { float f; u32 u; } a;
        a.u = ((u32)(u16)qf[ks][j]) << 16; a.f *= SCL; qf[ks][j] = (short)f2bf(a.f);
      }
    }
  }

  float mrow = -1e30f, lrow = 0.f;
  v16f oacc[2];
  oacc[0] = (v16f)0.f;
  oacc[1] = (v16f)0.f;

  // staging (R10-proven): 256 threads, 2 int4 per array, XOR-swizzled writes
  const int srow = tid >> 2;
  const int a3 = tid & 3;
  const int sw = srow & 7;
  const u16* kp_base = Kmat + base + (size_t)srow * DK + a3 * 16;
  const u16* vp_base = Vt + base + (size_t)srow * SEQ + a3 * 16;
  u16* krow = &K_lds[srow << 6];
  u16* vrow = &V_lds[srow << 6];

  int4 kr0, kr1, vr0, vr1;
#define A_LOAD(t)                                                  \
  do {                                                             \
    const u16* kp = kp_base + (size_t)(t) * 64 * DK;               \
    const u16* vp = vp_base + (t) * 64;                            \
    kr0 = ((const int4*)kp)[0];                                    \
    kr1 = ((const int4*)kp)[1];                                    \
    vr0 = ((const int4*)vp)[0];                                    \
    vr1 = ((const int4*)vp)[1];                                    \
  } while (0)
#define A_WRITE()                                                  \
  do {                                                             \
    *(int4*)((char*)krow + (((2 * a3 + 0) ^ sw) << 4)) = kr0;      \
    *(int4*)((char*)krow + (((2 * a3 + 1) ^ sw) << 4)) = kr1;      \
    *(int4*)((char*)vrow + (((2 * a3 + 0) ^ sw) << 4)) = vr0;      \
    *(int4*)((char*)vrow + (((2 * a3 + 1) ^ sw) << 4)) = vr1;      \
  } while (0)

  A_LOAD(0);

  for (int t = 0; t < SEQ / 64; ++t) {
    __syncthreads();   // all waves done reading tile t-1
    A_WRITE();
    __syncthreads();   // tile t visible
    if (t + 1 < SEQ / 64) A_LOAD(t + 1);  // loads fly under compute(t)

    // S^T[key][q] = K · Q^T : A-frag = K rows (m=key), B-frag = Q
    v16f sacc[2];
    sacc[0] = (v16f)0.f;
    sacc[1] = (v16f)0.f;
    __builtin_amdgcn_s_setprio(1);
#pragma unroll
    for (int ks = 0; ks < 4; ks++)
#pragma unroll
      for (int kb = 0; kb < 2; kb++) {
        v8s kf = lds_read_swz(K_lds, kb * 32 + l31, ks * 2 + h);
        sacc[kb] = __builtin_amdgcn_mfma_f32_32x32x16_bf16(kf, qf[ks], sacc[kb], 0, 0, 0);
      }
    __builtin_amdgcn_s_setprio(0);

    // lane owns 32 scores of its q column: tree max + one cross-half shfl
    float a0 = max3f(sacc[0][0], sacc[0][1], sacc[0][2]);
    float a1 = max3f(sacc[0][3], sacc[0][4], sacc[0][5]);
    float a2 = max3f(sacc[0][6], sacc[0][7], sacc[0][8]);
    float a3m = max3f(sacc[0][9], sacc[0][10], sacc[0][11]);
    float a4 = max3f(sacc[0][12], sacc[0][13], sacc[0][14]);
    float a5 = max3f(sacc[1][0], sacc[1][1], sacc[1][2]);
    float a6 = max3f(sacc[1][3], sacc[1][4], sacc[1][5]);
    float a7 = max3f(sacc[1][6], sacc[1][7], sacc[1][8]);
    float a8 = max3f(sacc[1][9], sacc[1][10], sacc[1][11]);
    float a9 = max3f(sacc[1][12], sacc[1][13], sacc[1][14]);
    float b0 = max3f(a0, a1, a2);
    float b1 = max3f(a3m, a4, sacc[0][15]);
    float b2 = max3f(a5, a6, a7);
    float b3 = max3f(a8, a9, sacc[1][15]);
    float mx = fmaxf(fmaxf(b0, b1), fmaxf(b2, b3));
    mx = fmaxf(mx, __shfl_xor(mx, 32));
    // defer-max: rescale only when max grew > 8 (log2 domain; P <= 256)
    if (__any(mx - mrow > 8.f)) {
      float mnew = fmaxf(mrow, mx);
      float fac = __builtin_amdgcn_exp2f(mrow - mnew);
#pragma unroll
      for (int i = 0; i < 16; i++) { oacc[0][i] *= fac; oacc[1][i] *= fac; }
      lrow *= fac;
      mrow = mnew;
    }
    // exp2 in place; l-sum in-lane + cross-half
    float ls = 0.f;
#pragma unroll
    for (int kb = 0; kb < 2; kb++)
#pragma unroll
      for (int i = 0; i < 16; i++) {
        sacc[kb][i] = __builtin_amdgcn_exp2f(sacc[kb][i] - mrow);
        ls += sacc[kb][i];
      }
    ls += __shfl_xor(ls, 32);
    lrow += ls;

    // PV: O^T[d][q] += V^T · P^T.  P B-frag assembled in-register via
    // v_permlane32_swap vdst,vsrc: vdst_HI-lanes <-> vsrc_LO-lanes.
    // Need lo-half's T2 <-> hi-half's T0  =>  swap(T0, T2):
    //   h=0: T0 kept (keys h8+0,1), T2 <- hi's T0 (keys 4,5 = h8+4,5)
    //   h=1: T0 <- lo's T2 (keys 8,9 = h8+0,1), T2 kept (keys 12,13)
    // likewise swap(T1, T3).  pw = {T0,T1,T2,T3} directly.
    __builtin_amdgcn_s_setprio(1);
#pragma unroll
    for (int kb = 0; kb < 2; kb++)
#pragma unroll
      for (int s = 0; s < 2; s++) {
        int T0 = cvtpk(sacc[kb][8 * s + 0], sacc[kb][8 * s + 1]);
        int T1 = cvtpk(sacc[kb][8 * s + 2], sacc[kb][8 * s + 3]);
        int T2 = cvtpk(sacc[kb][8 * s + 4], sacc[kb][8 * s + 5]);
        int T3 = cvtpk(sacc[kb][8 * s + 6], sacc[kb][8 * s + 7]);
        asm("v_permlane32_swap_b32 %0, %1" : "+v"(T0), "+v"(T2));
        asm("v_permlane32_swap_b32 %0, %1" : "+v"(T1), "+v"(T3));
        union { int4 i; v8s s8; } pw;
        pw.i.x = T0;   // keys ..+h8+0,1
        pw.i.y = T1;   // keys ..+h8+2,3
        pw.i.z = T2;   // keys ..+h8+4,5
        pw.i.w = T3;   // keys ..+h8+6,7
        const int st = kb * 2 + s;
#pragma unroll
        for (int db = 0; db < 2; db++) {
          v8s vf = lds_read_swz(V_lds, db * 32 + l31, st * 2 + h);
          oacc[db] = __builtin_amdgcn_mfma_f32_32x32x16_bf16(vf, pw.s8, oacc[db], 0, 0, 0);
        }
      }
    __builtin_amdgcn_s_setprio(0);
  }
#undef A_LOAD
#undef A_WRITE

  // epilogue: lane q=l31 owns O^T col; d = db*32 + 8g + 4h + {0..3}
  const int bb = bh >> 4, hh = bh & 15;
  const int q = qt * 128 + wv * 32 + l31;
  const float inv = 1.0f / lrow;
  const size_t rowbase = ((size_t)bb * SEQ + q) * HD + hh * DK;
#pragma unroll
  for (int db = 0; db < 2; db++)
#pragma unroll
    for (int g = 0; g < 4; g++) {
      int2 w;
      w.x = cvtpk(oacc[db][4 * g + 0] * inv, oacc[db][4 * g + 1] * inv);
      w.y = cvtpk(oacc[db][4 * g + 2] * inv, oacc[db][4 * g + 3] * inv);
      *(int2*)&AO[rowbase + db * 32 + g * 8 + h * 4] = w;
    }
}

extern "C" void kernel_launch(void* const* d_in, const int* in_sizes, int n_in,
                              void* d_out, int out_size, void* d_ws, size_t ws_size,
                              hipStream_t stream) {
  const float* q_in = (const float*)d_in[0];
  const float* k_in = (const float*)d_in[1];
  const float* v_in = (const float*)d_in[2];
  const float* Wq = (const float*)d_in[3];
  const float* Wk = (const float*)d_in[4];
  const float* Wv = (const float*)d_in[5];
  const float* Wo = (const float*)d_in[6];
  float* out = (float*)d_out;

  u16* ws = (u16*)d_ws;
  const size_t M1 = (size_t)1 << 20;
  u16* Wtq = ws;             // 4 x [1024][1024] bf16 (8MB)
  u16* Wtk = Wtq + M1;
  u16* Wtv = Wtk + M1;
  u16* Wto = Wtv + M1;
  u16* Qb = Wto + M1;                  // [B*H][S][64] bf16
  u16* Kb = Qb + (size_t)MROWS * HD;
  u16* VtB = Kb + (size_t)MROWS * HD;  // [B*H][64][S] bf16 (direct from GEMM)
  u16* AO = VtB + (size_t)MROWS * HD;  // [B*S][1024] bf16   (total 72MB)

  dim3 tb(256);
  wtrans4_kernel<<<dim3(16, 16, 4), tb, 0, stream>>>(Wq, Wk, Wv, Wo, Wtq, Wtk, Wtv, Wto);

  gemm_qkv_kernel<<<dim3(1536), tb, 0, stream>>>(q_in, k_in, v_in,
                                                 Wtq, Wtk, Wtv, Qb, Kb, VtB);

  attn_kernel<<<dim3(1024), tb, 0, stream>>>(Qb, Kb, VtB, AO);

  gemm_o_kernel<<<dim3(512), tb, 0, stream>>>(AO, Wto, out);
}

// Round 20
// 199.730 us; speedup vs baseline: 1.0288x; 1.0288x over previous
//
#include <hip/hip_runtime.h>
#include <hip/hip_bf16.h>

// MHA: fused QKV proj (one 1536-block launch, f32 A converted in staging,
// V-GEMM writes V^T) -> flash attn (8 waves/block, 16x16 MFMA) -> out proj.
// R20 = R17 (best measured config, 199.8us): banks all proven wins.
#define DIN   1024
#define HEADS 16
#define DK    64
#define BATCH 4
#define SEQ   2048
#define MROWS (BATCH*SEQ)   /* 8192 */
#define HD    (HEADS*DK)    /* 1024 */

typedef unsigned short u16;
typedef unsigned int   u32;
typedef __attribute__((ext_vector_type(8))) short v8s;
typedef __attribute__((ext_vector_type(4))) float v4f;

__device__ __forceinline__ u16 f2bf(float x) {
  union { float f; u32 u; } v; v.f = x;
  u32 r = v.u + 0x7FFFu + ((v.u >> 16) & 1u);
  return (u16)(r >> 16);
}
__device__ __forceinline__ int cvtpk(float lo, float hi) {
  int r;
  asm("v_cvt_pk_bf16_f32 %0, %1, %2" : "=v"(r) : "v"(lo), "v"(hi));
  return r;
}
__device__ __forceinline__ float max3f(float a, float b, float c) {
  float r;
  asm("v_max3_f32 %0, %1, %2, %3" : "=v"(r) : "v"(a), "v"(b), "v"(c));
  return r;
}
__device__ __forceinline__ void gload16(const void* g, void* l) {
  __builtin_amdgcn_global_load_lds(
      (__attribute__((address_space(1))) void*)(uintptr_t)(g),
      (__attribute__((address_space(3))) void*)(uintptr_t)(l), 16, 0, 0);
}
// swizzled access into flat [64 rows][8 units of 16B] tile: phys unit = u ^ (row&7)
__device__ __forceinline__ v8s lds_read_swz(const u16* base, int row, int unit) {
  return *(const v8s*)((const char*)base + (row << 7) + (((unit) ^ (row & 7)) << 4));
}

// ---- weight transpose x4: W[k][n] f32 -> Wt[n][k] bf16 ----
__global__ __launch_bounds__(256) void wtrans4_kernel(
    const float* __restrict__ w0, const float* __restrict__ w1,
    const float* __restrict__ w2, const float* __restrict__ w3,
    u16* __restrict__ o0, u16* __restrict__ o1,
    u16* __restrict__ o2, u16* __restrict__ o3) {
  __shared__ float tile[64][65];
  const float* in = blockIdx.z == 0 ? w0 : blockIdx.z == 1 ? w1 : blockIdx.z == 2 ? w2 : w3;
  u16* out = blockIdx.z == 0 ? o0 : blockIdx.z == 1 ? o1 : blockIdx.z == 2 ? o2 : o3;
  int bx = blockIdx.x * 64;
  int by = blockIdx.y * 64;
  for (int i = threadIdx.x; i < 64 * 64; i += 256) {
    int r = i >> 6, c = i & 63;
    tile[r][c] = in[(size_t)(by + r) * DIN + bx + c];
  }
  __syncthreads();
  for (int i = threadIdx.x; i < 64 * 64; i += 256) {
    int r = i >> 6, c = i & 63;
    out[(size_t)(bx + r) * DIN + by + c] = f2bf(tile[c][r]);
  }
}

// ---- fused QKV 128x128 GEMM: 1536 blocks, which = bid>>9 selects {Q,K,V}.
// A f32 reg-staged + fused cvt (T14); B bf16 DMA dbuf; 1 barrier / K-step.
// which 0/1: out bf16 scattered [B,H,S,dk]; which 2: out bf16 V^T [bh][d][s]. ----
__global__ __launch_bounds__(256) void gemm_qkv_kernel(
    const float* __restrict__ q_in, const float* __restrict__ k_in,
    const float* __restrict__ v_in, const u16* __restrict__ Wtq,
    const u16* __restrict__ Wtk, const u16* __restrict__ Wtv,
    u16* __restrict__ Qb, u16* __restrict__ Kb, u16* __restrict__ VtB) {
  __shared__ u16 A_lds[2][128 * 32];
  __shared__ u16 B_lds[2][128 * 32];
  const int which = blockIdx.x >> 9;  // 0..2
  const float* Ain = which == 0 ? q_in : which == 1 ? k_in : v_in;
  const u16* Bt = which == 0 ? Wtq : which == 1 ? Wtk : Wtv;
  u16* Cout = which == 0 ? Qb : which == 1 ? Kb : VtB;

  const int tid = threadIdx.x;
  const int lane = tid & 63;
  const int wv = tid >> 6;
  const int wm = wv & 1, wn = wv >> 1;
  const int bid = blockIdx.x & 511;
  const int swz = (bid & 7) * 64 + (bid >> 3);  // 512 % 8 == 0, bijective
  const int m0 = (swz >> 3) * 128;
  const int n0 = (swz & 7) * 128;
  const int l15 = lane & 15;
  const int k8 = (lane >> 4) * 8;

  const float* gaf = Ain + (size_t)(m0 + wv * 16 + (lane >> 2)) * DIN + (lane & 3) * 8;
  const u16* gb = Bt + (size_t)(n0 + wv * 16 + (lane >> 2)) * DIN + (lane & 3) * 8;
  u16* la0 = &A_lds[0][wv * 512 + (lane & 63) * 8];
  u16* la1 = &A_lds[1][wv * 512 + (lane & 63) * 8];

  v4f acc[4][4];
#pragma unroll
  for (int i = 0; i < 4; i++)
#pragma unroll
    for (int j = 0; j < 4; j++) acc[i][j] = (v4f)0.f;

  float4 af0, af1, af2, af3;

#define A_GLOAD(ks)                                                   \
  do {                                                                \
    af0 = ((const float4*)(gaf + (ks) * 32))[0];                      \
    af1 = ((const float4*)(gaf + (ks) * 32))[1];                      \
    af2 = ((const float4*)(gaf + (size_t)64 * DIN + (ks) * 32))[0];   \
    af3 = ((const float4*)(gaf + (size_t)64 * DIN + (ks) * 32))[1];   \
  } while (0)
#define A_DSWRITE(b)                                                  \
  do {                                                                \
    int4 w0 = {cvtpk(af0.x, af0.y), cvtpk(af0.z, af0.w),              \
               cvtpk(af1.x, af1.y), cvtpk(af1.z, af1.w)};             \
    int4 w1 = {cvtpk(af2.x, af2.y), cvtpk(af2.z, af2.w),              \
               cvtpk(af3.x, af3.y), cvtpk(af3.z, af3.w)};             \
    *(int4*)((b) ? la1 : la0) = w0;                                   \
    *(int4*)(((b) ? la1 : la0) + 2048) = w1;                          \
  } while (0)
#define B_STAGE(ks, b)                                                \
  do {                                                                \
    gload16(gb + (ks) * 32, &B_lds[b][wv * 512]);                     \
    gload16(gb + (size_t)64 * DIN + (ks) * 32, &B_lds[b][wv * 512 + 2048]); \
  } while (0)

  A_GLOAD(0);
  A_DSWRITE(0);
  B_STAGE(0, 0);
  __syncthreads();

  for (int ks = 0; ks < 32; ++ks) {
    const int buf = ks & 1;
    v8s a[4], b[4];
#pragma unroll
    for (int mi = 0; mi < 4; mi++)
      a[mi] = *(const v8s*)&A_lds[buf][(wm * 64 + mi * 16 + l15) * 32 + k8];
#pragma unroll
    for (int ni = 0; ni < 4; ni++)
      b[ni] = *(const v8s*)&B_lds[buf][(wn * 64 + ni * 16 + l15) * 32 + k8];
    if (ks < 31) {
      A_GLOAD(ks + 1);
      B_STAGE(ks + 1, buf ^ 1);
    }
    __builtin_amdgcn_s_setprio(1);
#pragma unroll
    for (int mi = 0; mi < 4; mi++)
#pragma unroll
      for (int ni = 0; ni < 4; ni++)
        acc[mi][ni] = __builtin_amdgcn_mfma_f32_16x16x32_bf16(a[mi], b[ni], acc[mi][ni], 0, 0, 0);
    __builtin_amdgcn_s_setprio(0);
    if (ks < 31) A_DSWRITE(buf ^ 1);  // vmcnt wait rode under MFMAs
    __syncthreads();
  }
#undef A_GLOAD
#undef A_DSWRITE
#undef B_STAGE

  const int grp = lane >> 4;
#pragma unroll
  for (int mi = 0; mi < 4; mi++) {
#pragma unroll
    for (int ni = 0; ni < 4; ni++) {
      int row = m0 + wm * 64 + mi * 16 + grp * 4;
      int col = n0 + wn * 64 + ni * 16 + l15;
      int w01 = cvtpk(acc[mi][ni][0], acc[mi][ni][1]);
      int w23 = cvtpk(acc[mi][ni][2], acc[mi][ni][3]);
      if (which < 2) {
        u16 h[4] = {(u16)w01, (u16)(w01 >> 16), (u16)w23, (u16)(w23 >> 16)};
#pragma unroll
        for (int r = 0; r < 4; r++) {
          int bb = (row + r) >> 11, ss = (row + r) & 2047;
          int hh = col >> 6, dd = col & 63;
          Cout[((((size_t)bb * HEADS + hh) * SEQ + ss) << 6) + dd] = h[r];
        }
      } else {
        // V^T: rows row..row+3 are 4 consecutive s at fixed (bb,hh,dd)
        int bb = row >> 11, ss = row & 2047;
        int hh = col >> 6, dd = col & 63;
        int2 w = {w01, w23};
        *(int2*)&Cout[((size_t)(bb * HEADS + hh) * DK + dd) * SEQ + ss] = w;
      }
    }
  }
}

// ---- 128x128 GEMM for Wo: bf16 A via DMA, out f32 linear ----
__global__ __launch_bounds__(256) void gemm_o_kernel(const u16* __restrict__ A,
                                                     const u16* __restrict__ Bt,
                                                     float* __restrict__ Cout) {
  __shared__ u16 A_lds[2][128 * 32];
  __shared__ u16 B_lds[2][128 * 32];
  const int tid = threadIdx.x;
  const int lane = tid & 63;
  const int wv = tid >> 6;
  const int wm = wv & 1, wn = wv >> 1;
  const int bid = blockIdx.x;
  const int swz = (bid & 7) * 64 + (bid >> 3);
  const int m0 = (swz >> 3) * 128;
  const int n0 = (swz & 7) * 128;
  const int l15 = lane & 15;
  const int k8 = (lane >> 4) * 8;

  const u16* ga = A + (size_t)(m0 + wv * 16 + (lane >> 2)) * DIN + (lane & 3) * 8;
  const u16* gb = Bt + (size_t)(n0 + wv * 16 + (lane >> 2)) * DIN + (lane & 3) * 8;

  v4f acc[4][4];
#pragma unroll
  for (int i = 0; i < 4; i++)
#pragma unroll
    for (int j = 0; j < 4; j++) acc[i][j] = (v4f)0.f;

#define G_STAGE(ks, b)                                              \
  do {                                                              \
    gload16(ga + (ks) * 32, &A_lds[b][wv * 512]);                   \
    gload16(ga + (size_t)64 * DIN + (ks) * 32, &A_lds[b][wv * 512 + 2048]); \
    gload16(gb + (ks) * 32, &B_lds[b][wv * 512]);                   \
    gload16(gb + (size_t)64 * DIN + (ks) * 32, &B_lds[b][wv * 512 + 2048]); \
  } while (0)

  G_STAGE(0, 0);
  __syncthreads();
  for (int ks = 0; ks < 32; ++ks) {
    const int buf = ks & 1;
    v8s a[4], b[4];
#pragma unroll
    for (int mi = 0; mi < 4; mi++)
      a[mi] = *(const v8s*)&A_lds[buf][(wm * 64 + mi * 16 + l15) * 32 + k8];
#pragma unroll
    for (int ni = 0; ni < 4; ni++)
      b[ni] = *(const v8s*)&B_lds[buf][(wn * 64 + ni * 16 + l15) * 32 + k8];
    if (ks < 31) G_STAGE(ks + 1, buf ^ 1);
    __builtin_amdgcn_s_setprio(1);
#pragma unroll
    for (int mi = 0; mi < 4; mi++)
#pragma unroll
      for (int ni = 0; ni < 4; ni++)
        acc[mi][ni] = __builtin_amdgcn_mfma_f32_16x16x32_bf16(a[mi], b[ni], acc[mi][ni], 0, 0, 0);
    __builtin_amdgcn_s_setprio(0);
    __syncthreads();
  }
#undef G_STAGE

  const int grp = lane >> 4;
#pragma unroll
  for (int mi = 0; mi < 4; mi++) {
#pragma unroll
    for (int ni = 0; ni < 4; ni++) {
#pragma unroll
      for (int r = 0; r < 4; r++) {
        int row = m0 + wm * 64 + mi * 16 + grp * 4 + r;
        int col = n0 + wn * 64 + ni * 16 + l15;
        Cout[(size_t)row * HD + col] = acc[mi][ni][r];
      }
    }
  }
}

// ---- flash attention: 8 waves/block, 128 q rows share staged K/V ----
__global__ __launch_bounds__(512) void attn_kernel(const u16* __restrict__ Q,
                                                   const u16* __restrict__ Kmat,
                                                   const u16* __restrict__ Vt,
                                                   u16* __restrict__ AO) {
  __shared__ u16 K_lds[64 * 64];   // [key][d] swizzled, 128B rows
  __shared__ u16 V_lds[64 * 64];   // [d][key] swizzled
  __shared__ u16 P_lds[8][16][72]; // per-wave P^T, padded linear

  const int tid = threadIdx.x;
  const int lane = tid & 63;
  const int wv = tid >> 6;         // 0..7
  const int l15 = lane & 15;
  const int grp = lane >> 4;
  const int k8 = grp * 8;

  const int bid = blockIdx.x;                    // 1024 blocks
  const int swz = (bid & 7) * 128 + (bid >> 3);  // 8 bh per XCD -> K/V L2-fit
  const int bh = swz >> 4;                       // 0..63
  const int qt = swz & 15;                       // 0..15
  const size_t base = (size_t)bh * SEQ * DK;

  // Q pre-scaled by (1/sqrt(64)) * log2(e) -> scores in log2 domain
  v8s qf[2];
  {
    const int q = qt * 128 + wv * 16 + l15;
    const u16* qp = Q + base + (size_t)q * DK;
    qf[0] = *(const v8s*)(qp + k8);
    qf[1] = *(const v8s*)(qp + 32 + k8);
    const float SCL = 0.125f * 1.44269504f;
#pragma unroll
    for (int j = 0; j < 8; j++) {
      union { float f; u32 u; } a;
      a.u = ((u32)(u16)qf[0][j]) << 16; a.f *= SCL; qf[0][j] = (short)f2bf(a.f);
      a.u = ((u32)(u16)qf[1][j]) << 16; a.f *= SCL; qf[1][j] = (short)f2bf(a.f);
    }
  }

  v8s ones;
#pragma unroll
  for (int j = 0; j < 8; j++) ones[j] = (short)0x3F80;  // bf16 1.0

  float mrow = -1e30f;
  v4f oacc[5];  // [0..3]: O^T d-blocks; [4]: l row-sum via ones-MFMA
#pragma unroll
  for (int db = 0; db < 5; db++) oacc[db] = (v4f)0.f;

  // staging: 512 threads, one 16B unit each per K and V
  const int srow = tid >> 3;     // 0..63
  const int au = tid & 7;        // unit within 128B row
  const int sw = srow & 7;
  const u16* kp_base = Kmat + base + (size_t)srow * DK + au * 8;
  const u16* vp_base = Vt + base + (size_t)srow * SEQ + au * 8;
  u16* krow = &K_lds[srow << 6];
  u16* vrow = &V_lds[srow << 6];

  int4 kr0, vr0;  // staging registers (issue-early / write-late)
#define A_LOAD(t)                                                  \
  do {                                                             \
    kr0 = *(const int4*)(kp_base + (size_t)(t) * 64 * DK);         \
    vr0 = *(const int4*)(vp_base + (t) * 64);                      \
  } while (0)
#define A_WRITE()                                                  \
  do {                                                             \
    *(int4*)((char*)krow + ((au ^ sw) << 4)) = kr0;                \
    *(int4*)((char*)vrow + ((au ^ sw) << 4)) = vr0;                \
  } while (0)

  A_LOAD(0);

  for (int t = 0; t < SEQ / 64; ++t) {
    __syncthreads();   // all waves done reading tile t-1
    A_WRITE();
    __syncthreads();   // tile t visible
    if (t + 1 < SEQ / 64) A_LOAD(t + 1);  // loads fly under compute(t)

    // S^T[key][q] = K · Q^T
    v4f sacc[4];
#pragma unroll
    for (int kb = 0; kb < 4; kb++) sacc[kb] = (v4f)0.f;
    __builtin_amdgcn_s_setprio(1);
#pragma unroll
    for (int ks = 0; ks < 2; ks++)
#pragma unroll
      for (int kb = 0; kb < 4; kb++) {
        v8s kf = lds_read_swz(K_lds, kb * 16 + l15, ks * 4 + grp);
        sacc[kb] = __builtin_amdgcn_mfma_f32_16x16x32_bf16(kf, qf[ks], sacc[kb], 0, 0, 0);
      }
    __builtin_amdgcn_s_setprio(0);

    // row max: max3 tree then cross-lane over grp
    float m1 = max3f(sacc[0][0], sacc[0][1], sacc[0][2]);
    float m2 = max3f(sacc[0][3], sacc[1][0], sacc[1][1]);
    float m3 = max3f(sacc[1][2], sacc[1][3], sacc[2][0]);
    float m4 = max3f(sacc[2][1], sacc[2][2], sacc[2][3]);
    float m5 = max3f(sacc[3][0], sacc[3][1], sacc[3][2]);
    float mx = fmaxf(max3f(m1, m2, m3), max3f(m4, m5, sacc[3][3]));
    mx = fmaxf(mx, __shfl_xor(mx, 16));
    mx = fmaxf(mx, __shfl_xor(mx, 32));
    // defer-max: rescale only when max grew > 8 (log2 domain; P <= 256)
    if (__any(mx - mrow > 8.f)) {
      float mnew = fmaxf(mrow, mx);
      float fac = __builtin_amdgcn_exp2f(mrow - mnew);
#pragma unroll
      for (int db = 0; db < 5; db++) oacc[db] *= fac;
      mrow = mnew;
    }
    float p[4][4];
#pragma unroll
    for (int kb = 0; kb < 4; kb++)
#pragma unroll
      for (int r = 0; r < 4; r++)
        p[kb][r] = __builtin_amdgcn_exp2f(sacc[kb][r] - mrow);

    // P^T -> per-wave LDS (b64 writes, cvt_pk packed)
#pragma unroll
    for (int kb = 0; kb < 4; kb++) {
      int2 w;
      w.x = cvtpk(p[kb][0], p[kb][1]);
      w.y = cvtpk(p[kb][2], p[kb][3]);
      *(int2*)&P_lds[wv][l15][kb * 16 + grp * 4] = w;
    }
    asm volatile("s_waitcnt lgkmcnt(0)" ::: "memory");

    // O^T += V^T · P^T ; 5th block (A=ones) accumulates l in the matrix pipe
    __builtin_amdgcn_s_setprio(1);
#pragma unroll
    for (int ks = 0; ks < 2; ks++) {
      v8s pf = *(const v8s*)&P_lds[wv][l15][ks * 32 + k8];
#pragma unroll
      for (int db = 0; db < 4; db++) {
        v8s vf = lds_read_swz(V_lds, db * 16 + l15, ks * 4 + grp);
        oacc[db] = __builtin_amdgcn_mfma_f32_16x16x32_bf16(vf, pf, oacc[db], 0, 0, 0);
      }
      oacc[4] = __builtin_amdgcn_mfma_f32_16x16x32_bf16(ones, pf, oacc[4], 0, 0, 0);
    }
    __builtin_amdgcn_s_setprio(0);
  }
#undef A_LOAD
#undef A_WRITE

  const int bb = bh >> 4, hh = bh & 15;
  const int q = qt * 128 + wv * 16 + l15;
  const float inv = 1.0f / oacc[4][0];
  const size_t rowbase = ((size_t)bb * SEQ + q) * HD + hh * DK;
#pragma unroll
  for (int db = 0; db < 4; db++) {
    int2 w;
    w.x = cvtpk(oacc[db][0] * inv, oacc[db][1] * inv);
    w.y = cvtpk(oacc[db][2] * inv, oacc[db][3] * inv);
    *(int2*)&AO[rowbase + db * 16 + grp * 4] = w;
  }
}

extern "C" void kernel_launch(void* const* d_in, const int* in_sizes, int n_in,
                              void* d_out, int out_size, void* d_ws, size_t ws_size,
                              hipStream_t stream) {
  const float* q_in = (const float*)d_in[0];
  const float* k_in = (const float*)d_in[1];
  const float* v_in = (const float*)d_in[2];
  const float* Wq = (const float*)d_in[3];
  const float* Wk = (const float*)d_in[4];
  const float* Wv = (const float*)d_in[5];
  const float* Wo = (const float*)d_in[6];
  float* out = (float*)d_out;

  u16* ws = (u16*)d_ws;
  const size_t M1 = (size_t)1 << 20;
  u16* Wtq = ws;             // 4 x [1024][1024] bf16 (8MB)
  u16* Wtk = Wtq + M1;
  u16* Wtv = Wtk + M1;
  u16* Wto = Wtv + M1;
  u16* Qb = Wto + M1;                  // [B*H][S][64] bf16
  u16* Kb = Qb + (size_t)MROWS * HD;
  u16* VtB = Kb + (size_t)MROWS * HD;  // [B*H][64][S] bf16 (direct from GEMM)
  u16* AO = VtB + (size_t)MROWS * HD;  // [B*S][1024] bf16   (total 72MB)

  dim3 tb(256);
  wtrans4_kernel<<<dim3(16, 16, 4), tb, 0, stream>>>(Wq, Wk, Wv, Wo, Wtq, Wtk, Wtv, Wto);

  gemm_qkv_kernel<<<dim3(1536), tb, 0, stream>>>(q_in, k_in, v_in,
                                                 Wtq, Wtk, Wtv, Qb, Kb, VtB);

  attn_kernel<<<dim3(1024), dim3(512), 0, stream>>>(Qb, Kb, VtB, AO);

  gemm_o_kernel<<<dim3(512), tb, 0, stream>>>(AO, Wto, out);
}